// Round 1
// baseline (631.675 us; speedup 1.0000x reference)
//
#include <hip/hip_runtime.h>
#include <hip/hip_bf16.h>
#include <stdint.h>

// y = x @ quant(w).T + bias
//   x: (8192, 4096) fp32   w: (4096, 4096) fp32 (OUT, IN)   bias: (4096,) fp32
//   out: (8192, 4096) fp32
// Strategy: per-tensor int8 quant/dequant of w -> bf16; x -> bf16; m97-style
// 128x128xBK32 MFMA GEMM with global_load_lds width=16 staging.

using short8  = __attribute__((ext_vector_type(8))) short;   // 8 bf16 = 4 VGPR
using float4v = __attribute__((ext_vector_type(4))) float;   // 4 fp32

// ---------- helpers ----------

__device__ __forceinline__ unsigned short f2bf(float f) {
    union { float f; uint32_t u; } v; v.f = f;
    uint32_t u = v.u;
    u += 0x7fffu + ((u >> 16) & 1u);   // RNE
    return (unsigned short)(u >> 16);
}

__device__ __forceinline__ void gload_lds16(const unsigned short* g, unsigned short* l) {
    __builtin_amdgcn_global_load_lds(
        (const __attribute__((address_space(1))) void*)g,
        (__attribute__((address_space(3))) void*)l,
        16, 0, 0);
}

// ---------- quantization pipeline ----------

__global__ void absmax_kernel(const float* __restrict__ w, int n4, unsigned int* __restrict__ out) {
    const float4* w4 = (const float4*)w;
    float m = 0.f;
    for (int i = blockIdx.x * blockDim.x + threadIdx.x; i < n4; i += gridDim.x * blockDim.x) {
        float4 v = w4[i];
        m = fmaxf(m, fmaxf(fmaxf(fabsf(v.x), fabsf(v.y)), fmaxf(fabsf(v.z), fabsf(v.w))));
    }
    #pragma unroll
    for (int off = 32; off > 0; off >>= 1)
        m = fmaxf(m, __shfl_down(m, off, 64));
    __shared__ float smax[8];
    int lane = threadIdx.x & 63, wv = threadIdx.x >> 6;
    if (lane == 0) smax[wv] = m;
    __syncthreads();
    if (threadIdx.x == 0) {
        float bm = smax[0];
        for (int i = 1; i < (int)(blockDim.x >> 6); i++) bm = fmaxf(bm, smax[i]);
        atomicMax(out, __float_as_uint(bm));   // all values >= 0: uint order == float order
    }
}

__global__ void quant_kernel(const float* __restrict__ w, int n4,
                             const unsigned int* __restrict__ amax_bits,
                             ushort4* __restrict__ wq) {
    const float amax  = __uint_as_float(*amax_bits);
    const float scale = amax / 127.0f;
    const float inv   = 1.0f / scale;
    const float4* w4 = (const float4*)w;
    for (int i = blockIdx.x * blockDim.x + threadIdx.x; i < n4; i += gridDim.x * blockDim.x) {
        float4 v = w4[i];
        float q0 = fminf(fmaxf(rintf(v.x * inv), -127.f), 127.f);
        float q1 = fminf(fmaxf(rintf(v.y * inv), -127.f), 127.f);
        float q2 = fminf(fmaxf(rintf(v.z * inv), -127.f), 127.f);
        float q3 = fminf(fmaxf(rintf(v.w * inv), -127.f), 127.f);
        ushort4 o;
        o.x = f2bf(q0 * scale); o.y = f2bf(q1 * scale);
        o.z = f2bf(q2 * scale); o.w = f2bf(q3 * scale);
        wq[i] = o;
    }
}

__global__ void cvt_bf16_kernel(const float4* __restrict__ in, ushort4* __restrict__ out, int n4) {
    for (int i = blockIdx.x * blockDim.x + threadIdx.x; i < n4; i += gridDim.x * blockDim.x) {
        float4 v = in[i];
        ushort4 o;
        o.x = f2bf(v.x); o.y = f2bf(v.y); o.z = f2bf(v.z); o.w = f2bf(v.w);
        out[i] = o;
    }
}

// ---------- GEMM: C(MxN) = A(MxK) * B(NxK)^T + bias, all-bf16 inputs, fp32 out ----------
// 128x128 block tile, BK=32, 256 threads (4 waves, 2x2), 4x4 16x16x32 MFMA per wave.

__global__ __launch_bounds__(256) void gemm_bt(
    const unsigned short* __restrict__ A,   // M x K bf16
    const unsigned short* __restrict__ B,   // N x K bf16 (weight rows along K)
    const float* __restrict__ bias,
    float* __restrict__ C,                  // M x N fp32
    int M, int N, int K)
{
    __shared__ __align__(16) unsigned short As[128 * 32];   // 8 KB
    __shared__ __align__(16) unsigned short Bs[128 * 32];   // 8 KB

    const int tid  = threadIdx.x;
    const int lane = tid & 63;
    const int wave = tid >> 6;
    const int wm   = wave >> 1;          // wave grid 2x2
    const int wn   = wave & 1;

    const int bm = blockIdx.y * 128;
    const int bn = blockIdx.x * 128;

    // --- staging: each wave fills 2x 1KB chunks of As and Bs via global_load_lds ---
    // issue i covers rows [i*16, i*16+16); lane l -> row i*16 + l/4, k-chunk (l%4)*8
    const int srow = wave * 32 + (lane >> 2);
    const int skc  = (lane & 3) * 8;

    const unsigned short* Ag0 = A + (size_t)(bm + srow) * K + skc;
    const unsigned short* Ag1 = Ag0 + (size_t)16 * K;
    const unsigned short* Bg0 = B + (size_t)(bn + srow) * K + skc;
    const unsigned short* Bg1 = Bg0 + (size_t)16 * K;

    unsigned short* sA0 = As + wave * 1024;
    unsigned short* sA1 = sA0 + 512;
    unsigned short* sB0 = Bs + wave * 1024;
    unsigned short* sB1 = sB0 + 512;

    // --- fragment read pointers (A-operand layout: m=lane&15, k=(lane>>4)*8+j) ---
    const int frow = lane & 15;
    const int fkc  = (lane >> 4) * 8;
    const unsigned short* pa = As + (wm * 64 + frow) * 32 + fkc;
    const unsigned short* pb = Bs + (wn * 64 + frow) * 32 + fkc;

    float4v acc[4][4];
    const float4v zero = {0.f, 0.f, 0.f, 0.f};
    #pragma unroll
    for (int i = 0; i < 4; i++)
        #pragma unroll
        for (int j = 0; j < 4; j++) acc[i][j] = zero;

    for (int k0 = 0; k0 < K; k0 += 32) {
        gload_lds16(Ag0, sA0);
        gload_lds16(Ag1, sA1);
        gload_lds16(Bg0, sB0);
        gload_lds16(Bg1, sB1);
        Ag0 += 32; Ag1 += 32; Bg0 += 32; Bg1 += 32;
        __syncthreads();   // compiler emits vmcnt(0) drain before s_barrier

        short8 a[4], b[4];
        #pragma unroll
        for (int i = 0; i < 4; i++) a[i] = *(const short8*)(pa + i * (16 * 32));
        #pragma unroll
        for (int j = 0; j < 4; j++) b[j] = *(const short8*)(pb + j * (16 * 32));

        #pragma unroll
        for (int i = 0; i < 4; i++)
            #pragma unroll
            for (int j = 0; j < 4; j++)
                acc[i][j] = __builtin_amdgcn_mfma_f32_16x16x32_bf16(a[i], b[j], acc[i][j], 0, 0, 0);

        __syncthreads();   // protect LDS before next overwrite
    }

    // --- epilogue: C/D layout col=lane&15, row=(lane>>4)*4+reg ---
    const int quad = lane >> 4;
    const int cl   = lane & 15;
    #pragma unroll
    for (int j = 0; j < 4; j++) {
        const int gc = bn + wn * 64 + j * 16 + cl;
        const float bs = bias[gc];
        #pragma unroll
        for (int i = 0; i < 4; i++) {
            const int gr = bm + wm * 64 + i * 16 + quad * 4;
            float* cp = C + (size_t)gr * N + gc;
            #pragma unroll
            for (int r = 0; r < 4; r++)
                cp[(size_t)r * N] = acc[i][j][r] + bs;
        }
    }
}

// ---------- launch ----------

extern "C" void kernel_launch(void* const* d_in, const int* in_sizes, int n_in,
                              void* d_out, int out_size, void* d_ws, size_t ws_size,
                              hipStream_t stream) {
    const float* x    = (const float*)d_in[0];   // (8192, 4096)
    const float* w    = (const float*)d_in[1];   // (4096, 4096)
    const float* bias = (const float*)d_in[2];   // (4096,)
    float* out = (float*)d_out;

    const int M = 8192, N = 4096, K = 4096;

    // workspace layout: [256B absmax slot | wq bf16 (N*K) | x bf16 chunk buffer]
    const size_t wq_off   = 256;
    const size_t wq_bytes = (size_t)N * K * 2;
    unsigned int*   amax = (unsigned int*)d_ws;
    unsigned short* wq   = (unsigned short*)((char*)d_ws + wq_off);
    unsigned short* xb   = (unsigned short*)((char*)d_ws + wq_off + wq_bytes);

    size_t avail = (ws_size > wq_off + wq_bytes) ? ws_size - wq_off - wq_bytes : 0;
    int nch = 1;
    while (nch < 64 && (size_t)(M / nch) * K * 2 > avail) nch <<= 1;
    const int crows = M / nch;   // multiple of 128 down to 128 at nch=64

    hipMemsetAsync(d_ws, 0, 256, stream);
    absmax_kernel<<<1024, 256, 0, stream>>>(w, (N * K) / 4, amax);
    quant_kernel<<<1024, 256, 0, stream>>>(w, (N * K) / 4, amax, (ushort4*)wq);

    for (int c = 0; c < nch; c++) {
        const float* xc = x + (size_t)c * crows * K;
        cvt_bf16_kernel<<<1024, 256, 0, stream>>>((const float4*)xc, (ushort4*)xb,
                                                  (crows * K) / 4);
        dim3 grid(N / 128, crows / 128);
        gemm_bt<<<grid, 256, 0, stream>>>(xb, wq, bias, out + (size_t)c * crows * N,
                                          crows, N, K);
    }
}

// Round 2
// 628.469 us; speedup vs baseline: 1.0051x; 1.0051x over previous
//
#include <hip/hip_runtime.h>
#include <hip/hip_bf16.h>
#include <stdint.h>

// y = x @ quant(w).T + bias
//   x: (8192, 4096) fp32   w: (4096, 4096) fp32 (OUT, IN)   bias: (4096,) fp32
// R2: rotation-swizzled LDS layout (kills the 8-way ds_read_b128 bank
// conflicts of the row-major tile), fused absmax+cvt pre-pass.

using short8  = __attribute__((ext_vector_type(8))) short;   // 8 bf16 = 4 VGPR
using float4v = __attribute__((ext_vector_type(4))) float;   // 4 fp32

// ---------- helpers ----------

__device__ __forceinline__ unsigned short f2bf(float f) {
    union { float f; uint32_t u; } v; v.f = f;
    uint32_t u = v.u;
    u += 0x7fffu + ((u >> 16) & 1u);   // RNE
    return (unsigned short)(u >> 16);
}

__device__ __forceinline__ void gload_lds16(const unsigned short* g, unsigned short* l) {
    __builtin_amdgcn_global_load_lds(
        (const __attribute__((address_space(1))) void*)g,
        (__attribute__((address_space(3))) void*)l,
        16, 0, 0);
}

// ---------- pre-pass 1: absmax(w) (blocks [0,AB)) + cvt x->bf16 (blocks [AB,AB+CB)) ----------

#define AB 1024
#define CB 2048

__global__ void prep_kernel(const float* __restrict__ w, int wn4,
                            const float4* __restrict__ x, ushort4* __restrict__ xb, int xn4,
                            unsigned int* __restrict__ amax_out) {
    if (blockIdx.x < AB) {
        // absmax over w
        const float4* w4 = (const float4*)w;
        float m = 0.f;
        for (int i = blockIdx.x * blockDim.x + threadIdx.x; i < wn4; i += AB * blockDim.x) {
            float4 v = w4[i];
            m = fmaxf(m, fmaxf(fmaxf(fabsf(v.x), fabsf(v.y)), fmaxf(fabsf(v.z), fabsf(v.w))));
        }
        #pragma unroll
        for (int off = 32; off > 0; off >>= 1)
            m = fmaxf(m, __shfl_down(m, off, 64));
        __shared__ float smax[4];
        int lane = threadIdx.x & 63, wv = threadIdx.x >> 6;
        if (lane == 0) smax[wv] = m;
        __syncthreads();
        if (threadIdx.x == 0) {
            float bm = fmaxf(fmaxf(smax[0], smax[1]), fmaxf(smax[2], smax[3]));
            atomicMax(amax_out, __float_as_uint(bm));  // vals >= 0: uint order == float order
        }
    } else {
        // x -> bf16
        for (int i = (blockIdx.x - AB) * blockDim.x + threadIdx.x; i < xn4; i += CB * blockDim.x) {
            float4 v = x[i];
            ushort4 o;
            o.x = f2bf(v.x); o.y = f2bf(v.y); o.z = f2bf(v.z); o.w = f2bf(v.w);
            xb[i] = o;
        }
    }
}

// ---------- pre-pass 2: quantize/dequant w -> bf16 ----------

__global__ void quant_kernel(const float* __restrict__ w, int n4,
                             const unsigned int* __restrict__ amax_bits,
                             ushort4* __restrict__ wq) {
    const float amax  = __uint_as_float(*amax_bits);
    const float scale = amax / 127.0f;
    const float inv   = 1.0f / scale;
    const float4* w4 = (const float4*)w;
    for (int i = blockIdx.x * blockDim.x + threadIdx.x; i < n4; i += gridDim.x * blockDim.x) {
        float4 v = w4[i];
        float q0 = fminf(fmaxf(rintf(v.x * inv), -127.f), 127.f);
        float q1 = fminf(fmaxf(rintf(v.y * inv), -127.f), 127.f);
        float q2 = fminf(fmaxf(rintf(v.z * inv), -127.f), 127.f);
        float q3 = fminf(fmaxf(rintf(v.w * inv), -127.f), 127.f);
        ushort4 o;
        o.x = f2bf(q0 * scale); o.y = f2bf(q1 * scale);
        o.z = f2bf(q2 * scale); o.w = f2bf(q3 * scale);
        wq[i] = o;
    }
}

// ---------- GEMM: C(MxN) = A(MxK) * B(NxK)^T + bias ----------
// 128x128 block tile, BK=32, 256 threads (2x2 waves), 4x4 16x16x32 MFMA/wave.
// LDS layout: per 16-row/1KB region, chunk position p = 4*r + ((kc + (r>>1)) & 3)
// (16B chunks). Rotation makes each quarter-wave ds_read_b128 phase hit all 8
// bank-groups exactly 2x (2-way aliasing is free on gfx950 — m136).

__global__ __launch_bounds__(256) void gemm_bt(
    const unsigned short* __restrict__ A,   // M x K bf16
    const unsigned short* __restrict__ B,   // N x K bf16
    const float* __restrict__ bias,
    float* __restrict__ C,                  // M x N fp32
    int M, int N, int K)
{
    __shared__ __align__(16) unsigned short As[128 * 32];   // 8 KB
    __shared__ __align__(16) unsigned short Bs[128 * 32];   // 8 KB

    const int tid  = threadIdx.x;
    const int lane = tid & 63;
    const int wave = tid >> 6;
    const int wm   = wave >> 1;
    const int wn   = wave & 1;

    const int bm = blockIdx.y * 128;
    const int bn = blockIdx.x * 128;

    // --- staging: lane l of each 1KB region issue -> row l>>2 (of 16),
    //     global kc rotated: kc = ((l&3) - (l>>3)) & 3  (inverse of read rot) ---
    const int srow = wave * 32 + (lane >> 2);
    const int skc  = (((lane & 3) - (lane >> 3)) & 3) * 8;

    const unsigned short* Ag0 = A + (size_t)(bm + srow) * K + skc;
    const unsigned short* Ag1 = Ag0 + (size_t)16 * K;
    const unsigned short* Bg0 = B + (size_t)(bn + srow) * K + skc;
    const unsigned short* Bg1 = Bg0 + (size_t)16 * K;

    unsigned short* sA0 = As + wave * 1024;
    unsigned short* sA1 = sA0 + 512;
    unsigned short* sB0 = Bs + wave * 1024;
    unsigned short* sB1 = sB0 + 512;

    // --- fragment read: row r = lane&15, chunk c = lane>>4;
    //     position within region p = 4r + ((c + (r>>1)) & 3), 8 elems/chunk ---
    const int frow = lane & 15;
    const int fc   = lane >> 4;
    const int poff = (frow * 4 + ((fc + (frow >> 1)) & 3)) * 8;
    const unsigned short* pa = As + wm * 64 * 32 + poff;
    const unsigned short* pb = Bs + wn * 64 * 32 + poff;

    float4v acc[4][4];
    const float4v zero = {0.f, 0.f, 0.f, 0.f};
    #pragma unroll
    for (int i = 0; i < 4; i++)
        #pragma unroll
        for (int j = 0; j < 4; j++) acc[i][j] = zero;

    for (int k0 = 0; k0 < K; k0 += 32) {
        gload_lds16(Ag0, sA0);
        gload_lds16(Ag1, sA1);
        gload_lds16(Bg0, sB0);
        gload_lds16(Bg1, sB1);
        Ag0 += 32; Ag1 += 32; Bg0 += 32; Bg1 += 32;
        __syncthreads();

        short8 a[4], b[4];
        #pragma unroll
        for (int i = 0; i < 4; i++) a[i] = *(const short8*)(pa + i * 512);
        #pragma unroll
        for (int j = 0; j < 4; j++) b[j] = *(const short8*)(pb + j * 512);

        #pragma unroll
        for (int i = 0; i < 4; i++)
            #pragma unroll
            for (int j = 0; j < 4; j++)
                acc[i][j] = __builtin_amdgcn_mfma_f32_16x16x32_bf16(a[i], b[j], acc[i][j], 0, 0, 0);

        __syncthreads();
    }

    // --- epilogue: C/D layout col=lane&15, row=(lane>>4)*4+reg ---
    const int quad = lane >> 4;
    const int cl   = lane & 15;
    #pragma unroll
    for (int j = 0; j < 4; j++) {
        const int gc = bn + wn * 64 + j * 16 + cl;
        const float bs = bias[gc];
        #pragma unroll
        for (int i = 0; i < 4; i++) {
            const int gr = bm + wm * 64 + i * 16 + quad * 4;
            float* cp = C + (size_t)gr * N + gc;
            #pragma unroll
            for (int r = 0; r < 4; r++)
                cp[(size_t)r * N] = acc[i][j][r] + bs;
        }
    }
}

// ---------- launch ----------

extern "C" void kernel_launch(void* const* d_in, const int* in_sizes, int n_in,
                              void* d_out, int out_size, void* d_ws, size_t ws_size,
                              hipStream_t stream) {
    const float* x    = (const float*)d_in[0];   // (M, K)
    const float* w    = (const float*)d_in[1];   // (N, K)
    const float* bias = (const float*)d_in[2];   // (N,)
    float* out = (float*)d_out;

    const int N = 4096, K = 4096;
    const int M = in_sizes[0] / K;               // 8192

    // workspace: [256B amax | wq bf16 N*K | xb bf16 chunk]
    const size_t wq_off   = 256;
    const size_t wq_bytes = (size_t)N * K * 2;
    unsigned int*   amax = (unsigned int*)d_ws;
    unsigned short* wq   = (unsigned short*)((char*)d_ws + wq_off);
    unsigned short* xb   = (unsigned short*)((char*)d_ws + wq_off + wq_bytes);

    size_t avail = (ws_size > wq_off + wq_bytes) ? ws_size - wq_off - wq_bytes : 0;
    int nch = 1;
    while (nch < 64 && (size_t)(M / nch) * K * 2 > avail) nch <<= 1;
    const int crows = M / nch;

    hipMemsetAsync(d_ws, 0, 256, stream);

    if (nch == 1) {
        prep_kernel<<<AB + CB, 256, 0, stream>>>(w, (N * K) / 4,
                                                 (const float4*)x, (ushort4*)xb, (M * K) / 4,
                                                 amax);
        quant_kernel<<<2048, 256, 0, stream>>>(w, (N * K) / 4, amax, (ushort4*)wq);
        dim3 grid(N / 128, M / 128);
        gemm_bt<<<grid, 256, 0, stream>>>(xb, wq, bias, out, M, N, K);
    } else {
        prep_kernel<<<AB, 256, 0, stream>>>(w, (N * K) / 4,
                                            (const float4*)x, (ushort4*)xb, 0, amax);
        quant_kernel<<<2048, 256, 0, stream>>>(w, (N * K) / 4, amax, (ushort4*)wq);
        for (int c = 0; c < nch; c++) {
            const float* xc = x + (size_t)c * crows * K;
            prep_kernel<<<CB, 256, 0, stream>>>(nullptr, 0, (const float4*)xc, (ushort4*)xb,
                                                (crows * K) / 4, amax);
            dim3 grid(N / 128, crows / 128);
            gemm_bt<<<grid, 256, 0, stream>>>(xb, wq, bias, out + (size_t)c * crows * N,
                                              crows, N, K);
        }
    }
}